// Round 3
// baseline (72.293 us; speedup 1.0000x reference)
//
#include <hip/hip_runtime.h>

// SoftToHardEncoder: B=16, L=16, H=64, W=64, NUM_CODES=64
// Outputs (concat, fp32): soft[B,H,W,L], hard[B,H,W,L], idx[B,H,W,L]
//
// SINGLE kernel, no global scratch (R2's cross-kernel d_ws dependence broke
// replay coherence across XCD L2s). Every block rebuilds the per-row sorted
// codebook + prefix/suffix exp tables in LDS (~2.8K cyc), then encodes 2048
// elements:
//   s = #codes <= z  (7-step binary search)
//   sum  = e^{-z}*PP[s] + e^{z}*QS[s],  wsum likewise with weights
//   argmin = nearer sorted neighbor, exact fp32 |z-w|, numpy first-wins ties
//   via 64-bit (value,index) sort keys + equal-value-run rep propagation.

namespace {
constexpr int kL = 16;
constexpr int kHW = 4096;
constexpr int kN = 1 << 20;              // 1,048,576 per output
constexpr int kRow = 66;                 // SW/RP row stride: [0]=-BIG,[1..64],[65]=+BIG
constexpr int kKRow = 65;                // key row stride (u64), padded
constexpr int kTStride = kL * kRow + 12; // 1068: staggers table banks
constexpr float kLog2e = 1.44269504088896340736f;
}

__global__ __launch_bounds__(256) void soft_to_hard_fused(
    const float* __restrict__ z,
    const float* __restrict__ codes,
    float* __restrict__ out)
{
    __shared__ unsigned long long K[kL * kKRow]; // sortable keys
    __shared__ float SW[kL * kRow];              // sorted values (ext)
    __shared__ float RP[kL * kRow];              // original index per slot (ext)
    __shared__ float tabs[4 * kTStride];         // PP, PW, QS, QW

    const int tid = threadIdx.x;
    const int row = tid >> 4;            // 0..15  (codebook row this thread owns)
    const int c0  = (tid & 15) << 2;     // 0..60  (4 codes per thread)

    // ---- A: load own 4 codes, build (value,index) sortable keys ----
    const float4 wv = *reinterpret_cast<const float4*>(codes + (row << 6) + c0);
    float v4[4] = {wv.x, wv.y, wv.z, wv.w};
    unsigned long long myk[4];
#pragma unroll
    for (int k = 0; k < 4; ++k) {
        unsigned int u = __float_as_uint(v4[k]);
        u ^= (u & 0x80000000u) ? 0xFFFFFFFFu : 0x80000000u;  // monotone map
        myk[k] = ((unsigned long long)u << 6) | (unsigned long long)(c0 + k);
        K[row * kKRow + c0 + k] = myk[k];
    }
    if (tid < kL) {
        SW[tid * kRow + 0]  = -3.0e38f;  RP[tid * kRow + 0]  = 1.0e9f;
        SW[tid * kRow + 65] =  3.0e38f;  RP[tid * kRow + 65] = 1.0e9f;
    }
    __syncthreads();

    // ---- B: rank by counting smaller keys (exact, unique), scatter ----
    {
        int r[4] = {0, 0, 0, 0};
        const unsigned long long* Kr = K + row * kKRow;
#pragma unroll 16
        for (int c2 = 0; c2 < 64; ++c2) {
            const unsigned long long k2 = Kr[c2];   // 4-way broadcast, no conflict
#pragma unroll
            for (int k = 0; k < 4; ++k) r[k] += (k2 < myk[k]);
        }
#pragma unroll
        for (int k = 0; k < 4; ++k) {
            SW[row * kRow + r[k] + 1] = v4[k];
            RP[row * kRow + r[k] + 1] = (float)(c0 + k);
        }
    }
    __syncthreads();

    // ---- C: propagate first-original-index across equal-value runs ----
    // (runs are sorted by original index, so min == left neighbor; 2 passes
    //  handle runs up to length 3 — longer is probability ~0 for normals)
    for (int pass = 0; pass < 2; ++pass) {
        float nrep[4];
#pragma unroll
        for (int k = 0; k < 4; ++k) {
            const int o = row * kRow + c0 + k + 1;
            const float a = SW[o], b = SW[o - 1];
            nrep[k] = (a == b) ? fminf(RP[o], RP[o - 1]) : RP[o];
        }
        __syncthreads();
#pragma unroll
        for (int k = 0; k < 4; ++k) RP[row * kRow + c0 + k + 1] = nrep[k];
        __syncthreads();
    }

    // ---- D: one wave builds 64 scans: 16 rows x {PP fwd, PW fwd, QS bwd, QW bwd}
    if (tid < 64) {
        const int drow = tid >> 2;
        const int kind = tid & 3;            // 0=PP 1=PW 2=QS 3=QW
        const bool fwd = kind < 2;
        const bool wgt = (kind & 1) != 0;
        float* T = tabs + kind * kTStride + drow * kRow;
        const float* S = SW + drow * kRow;
        const float sgn = fwd ? kLog2e : -kLog2e;
        float acc = 0.0f;
        T[fwd ? 0 : 64] = 0.0f;
        T[65] = 0.0f;
#pragma unroll 8
        for (int t = 1; t <= 64; ++t) {
            const int i = fwd ? t : 65 - t;
            const float v = S[i];
            const float e = exp2f(v * sgn);
            acc += wgt ? e * v : e;
            T[fwd ? i : i - 1] = acc;
        }
    }
    __syncthreads();

    // ---- E: encode 8 elements/thread ----
    const int g0  = blockIdx.x * 256 + tid;      // 0..131071
    const int l   = g0 & 15;
    const int hw  = (g0 >> 4) & (kHW - 1);
    const int b0  = g0 >> 16;                    // 0 or 1; b = b0 + 2k
    const int lrow = l * kRow;
    const float* SWr = SW + lrow;
    const float* RPr = RP + lrow;

    float zv[8];
#pragma unroll
    for (int k = 0; k < 8; ++k)
        zv[k] = z[((b0 + 2 * k) << 16) + (l << 12) + hw];   // z is [B,L,H,W]

    int p[8];
#pragma unroll
    for (int k = 0; k < 8; ++k) p[k] = 0;

    // p = #codes <= z, in [0,64]; clamped binary search, 8-way interleaved
#pragma unroll
    for (int step = 64; step >= 1; step >>= 1) {
#pragma unroll
        for (int k = 0; k < 8; ++k) {
            const int t = p[k] + step;
            const float v = SWr[(t <= 64) ? t : 64];
            p[k] = (t <= 64 && v <= zv[k]) ? t : p[k];
        }
    }

#pragma unroll
    for (int k = 0; k < 8; ++k) {
        const int o = p[k];
        const float vlo = SWr[o], vhi = SWr[o + 1];
        const float rlo = RPr[o], rhi = RPr[o + 1];
        const int to = lrow + o;
        const float pp = tabs[to];
        const float pw = tabs[kTStride + to];
        const float qs = tabs[2 * kTStride + to];
        const float qw = tabs[3 * kTStride + to];

        const float t    = zv[k] * kLog2e;
        const float E    = exp2f(t);
        const float Einv = exp2f(-t);
        const float sum  = __builtin_fmaf(Einv, pp, E * qs);
        const float wsum = __builtin_fmaf(Einv, pw, E * qw);

        const float dlo = __builtin_fabsf(zv[k] - vlo);
        const float dhi = __builtin_fabsf(vhi - zv[k]);
        const bool takelo = (dlo < dhi) || (dlo == dhi && rlo < rhi);

        const int e = g0 + (k << 17);
        out[e]           = wsum * __builtin_amdgcn_rcpf(sum);
        out[kN + e]      = takelo ? vlo : vhi;
        out[2 * kN + e]  = takelo ? rlo : rhi;
    }
}

extern "C" void kernel_launch(void* const* d_in, const int* in_sizes, int n_in,
                              void* d_out, int out_size, void* d_ws, size_t ws_size,
                              hipStream_t stream) {
    const float* z     = (const float*)d_in[0];  // [16,16,64,64] fp32
    const float* codes = (const float*)d_in[1];  // [16,64] fp32
    float* out = (float*)d_out;                  // 3 * 1,048,576 fp32

    soft_to_hard_fused<<<512, 256, 0, stream>>>(z, codes, out);
}